// Round 3
// baseline (134.765 us; speedup 1.0000x reference)
//
#include <hip/hip_runtime.h>

#define HID 768
#define NTHREADS 256
#define WPB 4            // waves per block
#define MAXD_UNROLL 24   // steps fully unrolled for d < 24; runtime tail after

// One block per token t (2048 blocks x 4 waves). Wave w handles path steps
// d = s*4 + w, s = 0..5, fully unrolled with NO break so the per-step
// mask -> node -> W-gather chains are independent and pipeline.
// h[t] fragment lives in registers (6 x float2 per lane, loaded once).
// Each step: 6 coalesced float4 loads of W[n], 24 FMAs, 12-shfl butterfly,
// double-softmax CE computed redundantly on all lanes (no divergence).
// Block combines 4 wave-sums in LDS, one atomicAdd per block.
__global__ __launch_bounds__(NTHREADS) void huffman_tok_kernel(
    const float* __restrict__ hidden,       // [T, H]
    const int*   __restrict__ target,       // [T]
    const float* __restrict__ node_W,       // [V-1, H, 2]
    const float* __restrict__ node_b,       // [V-1, 2]
    const int*   __restrict__ path_nodes,   // [V, D]
    const int*   __restrict__ path_bits,    // [V, D]
    const void*  __restrict__ path_mask,    // [V, D] bool (byte OR int32 layout)
    float*       __restrict__ out,          // [1], pre-zeroed
    int D)
{
    const int t    = blockIdx.x;
    const int wave = threadIdx.x >> 6;
    const int lane = threadIdx.x & 63;

    // h fragment in registers: pair p = j*64+lane -> k = 2p, 2p+1.
    const float2* __restrict__ h2 = (const float2*)(hidden + (long)t * HID);
    float2 hreg[HID / 2 / 64];               // 6 x float2
    #pragma unroll
    for (int j = 0; j < HID / 2 / 64; ++j) hreg[j] = h2[j * 64 + lane];

    // Mask layout detect: mask[0,0..3] all true (min Huffman depth >> 4),
    // byte layout reads 0x01010101, int32 layout reads 1.
    const bool mask_is_byte = (*(const unsigned int*)path_mask) > 1u;
    const unsigned char* __restrict__ pm8  = (const unsigned char*)path_mask;
    const int*           __restrict__ pm32 = (const int*)path_mask;

    const int v = target[t];                 // block-uniform -> scalar load
    const long prow = (long)v * D;

    float lsum = 0.0f;

    auto do_step = [&](int d) {
        bool valid = (d < D);
        if (valid) valid = mask_is_byte ? (pm8[prow + d] != 0)
                                        : (pm32[prow + d] != 0);
        const long pidx = valid ? (prow + d) : prow;   // in-bounds always
        const int  n    = valid ? path_nodes[pidx] : 0;

        const float4* __restrict__ w4 =
            (const float4*)(node_W + (long)n * (HID * 2));

        float acc0 = 0.0f, acc1 = 0.0f;
        #pragma unroll
        for (int j = 0; j < HID / 2 / 64; ++j) {       // 6 float4 loads
            const float4 w = w4[j * 64 + lane];
            const float2 h = hreg[j];
            acc0 += h.x * w.x + h.y * w.z;
            acc1 += h.x * w.y + h.y * w.w;
        }
        #pragma unroll
        for (int off = 32; off > 0; off >>= 1) {
            acc0 += __shfl_xor(acc0, off, 64);
            acc1 += __shfl_xor(acc1, off, 64);
        }
        const float l0 = acc0 + node_b[n * 2 + 0];
        const float l1 = acc1 + node_b[n * 2 + 1];
        const float m  = fmaxf(l0, l1);
        const float e0 = __expf(l0 - m);
        const float e1 = __expf(l1 - m);
        const float s  = e0 + e1;
        const float p0 = e0 / s;
        const float p1 = e1 / s;
        const float lse = __logf(__expf(p0) + __expf(p1));
        const float pb  = path_bits[pidx] ? p1 : p0;
        lsum += valid ? (lse - pb) : 0.0f;
    };

    #pragma unroll
    for (int s = 0; s < MAXD_UNROLL / WPB; ++s)        // 6 unrolled steps
        do_step(s * WPB + wave);
    for (int d = MAXD_UNROLL + wave; d < D; d += WPB)  // safety tail (0-trip)
        do_step(d);

    // Block reduce: 4 wave sums -> 1 atomic.
    __shared__ float wsum[WPB];
    if (lane == 0) wsum[wave] = lsum;
    __syncthreads();
    if (threadIdx.x == 0) {
        float tot = 0.0f;
        #pragma unroll
        for (int w = 0; w < WPB; ++w) tot += wsum[w];
        atomicAdd(out, tot);
    }
}

extern "C" void kernel_launch(void* const* d_in, const int* in_sizes, int n_in,
                              void* d_out, int out_size, void* d_ws, size_t ws_size,
                              hipStream_t stream) {
    const float* hidden     = (const float*)d_in[0];
    const int*   target     = (const int*)d_in[1];
    const float* node_W     = (const float*)d_in[2];
    const float* node_b     = (const float*)d_in[3];
    const int*   path_nodes = (const int*)d_in[4];
    const int*   path_bits  = (const int*)d_in[5];
    const void*  path_mask  = (const void*)d_in[6];
    float* out = (float*)d_out;

    const int T   = in_sizes[0] / HID;        // B*S = 2048
    const int Vm1 = in_sizes[3] / 2;          // V-1
    const int V   = Vm1 + 1;
    const int D   = in_sizes[4] / V;          // padded path depth (~20)

    // out is re-poisoned (0xAA) before every timed call; zero it for atomics.
    hipMemsetAsync(d_out, 0, sizeof(float), stream);

    huffman_tok_kernel<<<dim3(T), dim3(NTHREADS), 0, stream>>>(
        hidden, target, node_W, node_b, path_nodes, path_bits, path_mask,
        out, D);
}

// Round 4
// 131.533 us; speedup vs baseline: 1.0246x; 1.0246x over previous
//
#include <hip/hip_runtime.h>

#define HID 768
#define NTHREADS 256
#define WPB 4            // waves per block
#define NPJ (HID / 2 / 16)   // 24 k-pairs per lane (16 lanes per step)

// One block per token t (2048 blocks x 4 waves). Each wave processes FOUR
// path steps at once: 16-lane group g (lanes g*16..g*16+15) owns step
// d = r*16 + wave*4 + g. Per round, per wave: 24 coalesced float4 W-loads
// + 48 FMAs cover all 4 steps; reduction is only 4 butterfly levels over
// 16 lanes (8 swizzles per round vs 96 in the 64-lane-per-step version).
// Rounds where no group has a valid step are skipped wave-uniformly via
// __ballot — for avg depth ~13, round 1 (d>=16) is skipped for most tokens.
// h[t] fragment (24 x float2) lives in registers, loaded once.
__global__ __launch_bounds__(NTHREADS) void huffman_g16_kernel(
    const float* __restrict__ hidden,       // [T, H]
    const int*   __restrict__ target,       // [T]
    const float* __restrict__ node_W,       // [V-1, H, 2]
    const float* __restrict__ node_b,       // [V-1, 2]
    const int*   __restrict__ path_nodes,   // [V, D]
    const int*   __restrict__ path_bits,    // [V, D]
    const void*  __restrict__ path_mask,    // [V, D] bool (byte OR int32 layout)
    float*       __restrict__ out,          // [1], pre-zeroed
    int D)
{
    const int t    = blockIdx.x;
    const int tid  = threadIdx.x;
    const int wave = tid >> 6;
    const int lane = tid & 63;
    const int g    = lane >> 4;     // step-group within wave (0..3)
    const int m    = lane & 15;     // lane within group

    // h fragment: lane m owns k-pairs p = j*16 + m, j = 0..23 (k = 2p, 2p+1).
    // Identical across groups/waves -> broadcast-friendly loads.
    const float2* __restrict__ h2 = (const float2*)(hidden + (long)t * HID);
    float2 hreg[NPJ];
    #pragma unroll
    for (int j = 0; j < NPJ; ++j) hreg[j] = h2[j * 16 + m];

    // Mask layout detect: mask[0,0..3] all true (min Huffman depth >> 4),
    // byte layout reads 0x01010101, int32 layout reads 1.
    const bool mask_is_byte = (*(const unsigned int*)path_mask) > 1u;
    const unsigned char* __restrict__ pm8  = (const unsigned char*)path_mask;
    const int*           __restrict__ pm32 = (const int*)path_mask;

    const int  v    = target[t];
    const long prow = (long)v * D;

    float lsum = 0.0f;
    const int rounds = (D + 15) >> 4;

    for (int r = 0; r < rounds; ++r) {
        const int d = r * 16 + wave * 4 + g;

        bool valid = (d < D);
        if (valid) valid = mask_is_byte ? (pm8[prow + d] != 0)
                                        : (pm32[prow + d] != 0);

        // Wave-uniform skip: valid steps are a prefix, so late rounds are
        // all-invalid for most tokens.
        if (__ballot(valid) == 0ull) continue;

        const long pidx = valid ? (prow + d) : prow;   // in-bounds always
        const int  n    = valid ? path_nodes[pidx] : 0;

        const float4* __restrict__ w4 =
            (const float4*)(node_W + (long)n * (HID * 2));

        float acc0 = 0.0f, acc1 = 0.0f;
        #pragma unroll
        for (int j = 0; j < NPJ; ++j) {                // 24 float4 loads/lane
            const float4 w = w4[j * 16 + m];           // pairs p=j*16+m, coalesced per group
            const float2 h = hreg[j];
            acc0 += h.x * w.x + h.y * w.z;
            acc1 += h.x * w.y + h.y * w.w;
        }

        // Reduce within 16-lane group: 4 levels x 2 accs.
        #pragma unroll
        for (int off = 8; off > 0; off >>= 1) {
            acc0 += __shfl_xor(acc0, off, 64);
            acc1 += __shfl_xor(acc1, off, 64);
        }

        // Double-softmax CE (computed redundantly on all 16 lanes of a group;
        // one wave-instruction serves all 4 groups).
        const float l0 = acc0 + node_b[n * 2 + 0];
        const float l1 = acc1 + node_b[n * 2 + 1];
        const float mx = fmaxf(l0, l1);
        const float e0 = __expf(l0 - mx);
        const float e1 = __expf(l1 - mx);
        const float s  = e0 + e1;
        const float p0 = e0 / s;
        const float p1 = e1 / s;
        const float lse = __logf(__expf(p0) + __expf(p1));
        const float pb  = path_bits[pidx] ? p1 : p0;
        lsum += (valid && m == 0) ? (lse - pb) : 0.0f;
    }

    // Wave reduce (only m==0 lanes hold nonzero), then block reduce -> atomic.
    #pragma unroll
    for (int off = 32; off > 0; off >>= 1) lsum += __shfl_xor(lsum, off, 64);

    __shared__ float wsum[WPB];
    if (lane == 0) wsum[wave] = lsum;
    __syncthreads();
    if (tid == 0) {
        float tot = 0.0f;
        #pragma unroll
        for (int w = 0; w < WPB; ++w) tot += wsum[w];
        atomicAdd(out, tot);
    }
}

extern "C" void kernel_launch(void* const* d_in, const int* in_sizes, int n_in,
                              void* d_out, int out_size, void* d_ws, size_t ws_size,
                              hipStream_t stream) {
    const float* hidden     = (const float*)d_in[0];
    const int*   target     = (const int*)d_in[1];
    const float* node_W     = (const float*)d_in[2];
    const float* node_b     = (const float*)d_in[3];
    const int*   path_nodes = (const int*)d_in[4];
    const int*   path_bits  = (const int*)d_in[5];
    const void*  path_mask  = (const void*)d_in[6];
    float* out = (float*)d_out;

    const int T   = in_sizes[0] / HID;        // B*S = 2048
    const int Vm1 = in_sizes[3] / 2;          // V-1
    const int V   = Vm1 + 1;
    const int D   = in_sizes[4] / V;          // padded path depth (~20)

    // out is re-poisoned (0xAA) before every timed call; zero it for atomics.
    hipMemsetAsync(d_out, 0, sizeof(float), stream);

    huffman_g16_kernel<<<dim3(T), dim3(NTHREADS), 0, stream>>>(
        hidden, target, node_W, node_b, path_nodes, path_bits, path_mask,
        out, D);
}